// Round 1
// baseline (665.191 us; speedup 1.0000x reference)
//
#include <hip/hip_runtime.h>
#include <cstdint>

typedef __attribute__((ext_vector_type(8))) short bf16x8;
typedef __attribute__((ext_vector_type(4))) float f32x4;

__device__ inline unsigned short f2bf(float f) {
  uint32_t u = __float_as_uint(f);
  uint32_t lsb = (u >> 16) & 1u;
  u += 0x7fffu + lsb;
  return (unsigned short)(u >> 16);
}
__device__ inline float bf2f(unsigned short b) {
  return __uint_as_float(((uint32_t)b) << 16);
}

#define GLOAD16(gp, lp)                                                        \
  __builtin_amdgcn_global_load_lds(                                            \
      (const __attribute__((address_space(1))) void*)(gp),                     \
      (__attribute__((address_space(3))) void*)(lp), 16, 0, 0)

// ---------------------------------------------------------------- converts
__global__ void cvt_f32_bf16(const float* __restrict__ in,
                             unsigned short* __restrict__ out, int n) {
  int i = (blockIdx.x * 256 + threadIdx.x) * 4;
  if (i >= n) return;
  float4 v = *(const float4*)(in + i);
  unsigned short o[4] = {f2bf(v.x), f2bf(v.y), f2bf(v.z), f2bf(v.w)};
  *(uint64_t*)(out + i) = *(const uint64_t*)o;
}

// ---------------------------------------------------------------- rope table
__global__ void rope_table_k(float* __restrict__ ctab, float* __restrict__ stab) {
  int i = blockIdx.x * 256 + threadIdx.x;  // 2048*64 entries
  int s = i >> 6, j = i & 63;
  // inv_freq = 10000^(-j/64) = exp(-j * ln(10000)/64)
  float invf = expf(-(float)j * (9.210340371976184f / 64.0f));
  float ang = (float)s * invf;
  ctab[i] = cosf(ang);
  stab[i] = sinf(ang);
}

// ---------------------------------------------------------------- rope apply (in-place on bf16 Q,K)
// rows: [buf(2)][bh(32)][s(2048)], 4 rows per 256-thread block
__global__ void rope_apply_k(unsigned short* __restrict__ qb,
                             unsigned short* __restrict__ kb,
                             const float* __restrict__ ctab,
                             const float* __restrict__ stab) {
  int row = blockIdx.x * 4 + (threadIdx.x >> 6);
  int t = threadIdx.x & 63;
  int s = row & 2047;
  int bh = (row >> 11) & 31;
  unsigned short* base = (row >> 16) ? kb : qb;
  unsigned short* p = base + ((size_t)bh * 2048 + s) * 128;
  float c = ctab[s * 64 + t], sn = stab[s * 64 + t];
  float x1 = bf2f(p[t]), x2 = bf2f(p[t + 64]);
  p[t] = f2bf(x1 * c - x2 * sn);
  p[t + 64] = f2bf(x2 * c + x1 * sn);
}

// ---------------------------------------------------------------- V transpose: [bh][s][d] -> [bh][d][s]
__global__ void transpose_v_k(const unsigned short* __restrict__ v,
                              unsigned short* __restrict__ vt) {
  __shared__ unsigned short tile[64][72];
  int bh = blockIdx.x, st = blockIdx.y, dt = blockIdx.z;
  const unsigned short* src = v + ((size_t)bh * 2048 + st * 64) * 128 + dt * 64;
  unsigned short* dst = vt + ((size_t)bh * 128 + dt * 64) * 2048 + st * 64;
  int t = threadIdx.x;
  int r = t >> 2, c0 = (t & 3) * 16;
  *(bf16x8*)&tile[r][c0] = *(const bf16x8*)(src + (size_t)r * 128 + c0);
  *(bf16x8*)&tile[r][c0 + 8] = *(const bf16x8*)(src + (size_t)r * 128 + c0 + 8);
  __syncthreads();
  unsigned short o[16];
#pragma unroll
  for (int i = 0; i < 16; i++) o[i] = tile[c0 + i][r];
  *(bf16x8*)(dst + (size_t)r * 2048 + c0) = *(const bf16x8*)&o[0];
  *(bf16x8*)(dst + (size_t)r * 2048 + c0 + 8) = *(const bf16x8*)&o[8];
}

// ---------------------------------------------------------------- GEMM C = A(MxK) * B(NxK)^T, bf16 in, m97 structure
// EPI 0: f32 row-major C.  EPI 1: bf16 scatter into Q/K/V [B][H][S][hd].
template <int EPI>
__global__ __launch_bounds__(256, 2) void gemm_bt(
    const unsigned short* __restrict__ A, const unsigned short* __restrict__ Bm,
    float* __restrict__ Cf, unsigned short* __restrict__ q_out,
    unsigned short* __restrict__ k_out, unsigned short* __restrict__ v_out,
    int M, int N, int K) {
  __shared__ unsigned short sA[128 * 32];
  __shared__ unsigned short sB[128 * 32];
  const int t = threadIdx.x;
  const int w = t >> 6, l = t & 63;
  const int wr = w >> 1, wc = w & 1;
  const int bm = blockIdx.x * 128, bn = blockIdx.y * 128;
  const int lr = l & 15, lg = l >> 4;
  f32x4 acc[4][4] = {};

  const int srow = w * 16 + (l >> 2);
  const int sseg = (l & 3) * 8;
  const unsigned short* ga = A + (size_t)(bm + srow) * K + sseg;
  const unsigned short* gb = Bm + (size_t)(bn + srow) * K + sseg;
  unsigned short* lA = sA + w * 512 + l * 8;  // bytes: w*1024 + l*16
  unsigned short* lB = sB + w * 512 + l * 8;

  for (int kt = 0; kt < K; kt += 32) {
    __syncthreads();
    GLOAD16(ga + kt, lA);
    GLOAD16(ga + kt + (size_t)64 * K, lA + 2048);
    GLOAD16(gb + kt, lB);
    GLOAD16(gb + kt + (size_t)64 * K, lB + 2048);
    __syncthreads();
    bf16x8 af[4], bfv[4];
#pragma unroll
    for (int m = 0; m < 4; m++)
      af[m] = *(const bf16x8*)(sA + (wr * 64 + m * 16 + lr) * 32 + lg * 8);
#pragma unroll
    for (int n = 0; n < 4; n++)
      bfv[n] = *(const bf16x8*)(sB + (wc * 64 + n * 16 + lr) * 32 + lg * 8);
#pragma unroll
    for (int m = 0; m < 4; m++)
#pragma unroll
      for (int n = 0; n < 4; n++)
        acc[m][n] = __builtin_amdgcn_mfma_f32_16x16x32_bf16(af[m], bfv[n],
                                                            acc[m][n], 0, 0, 0);
  }

#pragma unroll
  for (int m = 0; m < 4; m++) {
#pragma unroll
    for (int n = 0; n < 4; n++) {
      int gm0 = bm + wr * 64 + m * 16 + lg * 4;
      int gn = bn + wc * 64 + n * 16 + lr;
#pragma unroll
      for (int j = 0; j < 4; j++) {
        float v = acc[m][n][j];
        int gm = gm0 + j;
        if (EPI == 0) {
          Cf[(size_t)gm * N + gn] = v;
        } else {
          int which = gn >> 11, rem = gn & 2047;
          int h = rem >> 7, d = rem & 127;
          int b = gm >> 11, s = gm & 2047;
          unsigned short* dst = which == 0 ? q_out : (which == 1 ? k_out : v_out);
          dst[(((size_t)(b * 16 + h)) * 2048 + s) * 128 + d] = f2bf(v);
        }
      }
    }
  }
}

// ---------------------------------------------------------------- flash attention
// grid (bh=32, qtile=32), 256 threads = 4 independent waves, 16 q-rows each.
// Swapped QK^T (mfma(K,Q)) so softmax stats are lane-local per q-row (q = lane&15).
__global__ __launch_bounds__(256, 2) void attn_k(
    const unsigned short* __restrict__ Q, const unsigned short* __restrict__ K,
    const unsigned short* __restrict__ Vt, unsigned short* __restrict__ ctx) {
  __shared__ unsigned short plds[4][16 * 40];  // per-wave P buffer, stride 40 (conflict-free)
  const int bh = blockIdx.x, qt = blockIdx.y;
  const int w = threadIdx.x >> 6, l = threadIdx.x & 63;
  const int lr = l & 15, lg = l >> 4;
  const int b = bh >> 4, h = bh & 15;
  const int q0 = qt * 64 + w * 16;
  const unsigned short* Qp = Q + ((size_t)bh * 2048 + q0) * 128;
  const unsigned short* Kp = K + (size_t)bh * 2048 * 128;
  const unsigned short* Vp = Vt + (size_t)bh * 128 * 2048;

  bf16x8 qf[4];
#pragma unroll
  for (int ks = 0; ks < 4; ks++)
    qf[ks] = *(const bf16x8*)(Qp + lr * 128 + ks * 32 + lg * 8);

  f32x4 o[8];
#pragma unroll
  for (int i = 0; i < 8; i++) o[i] = (f32x4)0.0f;
  float m_r = -1e30f, l_r = 0.0f;
  const float scale = 0.08838834764831845f;  // 1/sqrt(128)
  unsigned short* pl = plds[w];

  for (int kv = 0; kv < 2048; kv += 32) {
    // S^T = K_tile * Q^T : lane holds scores for q-row lr, keys mf*16+lg*4+j
    f32x4 st[2];
#pragma unroll
    for (int mf = 0; mf < 2; mf++) {
      st[mf] = (f32x4)0.0f;
      const unsigned short* kp = Kp + ((size_t)(kv + mf * 16 + lr)) * 128 + lg * 8;
#pragma unroll
      for (int ks = 0; ks < 4; ks++) {
        bf16x8 kf = *(const bf16x8*)(kp + ks * 32);
        st[mf] = __builtin_amdgcn_mfma_f32_16x16x32_bf16(kf, qf[ks], st[mf], 0, 0, 0);
      }
    }
    float sm[8];
    float tmax = -1e30f;
#pragma unroll
    for (int i = 0; i < 8; i++) {
      sm[i] = st[i >> 2][i & 3] * scale;
      tmax = fmaxf(tmax, sm[i]);
    }
    tmax = fmaxf(tmax, __shfl_xor(tmax, 16));
    tmax = fmaxf(tmax, __shfl_xor(tmax, 32));
    float m_new = fmaxf(m_r, tmax);
    float fac = __expf(m_r - m_new);
    float psum = 0.0f;
#pragma unroll
    for (int i = 0; i < 8; i++) {
      sm[i] = __expf(sm[i] - m_new);
      psum += sm[i];
    }
    psum += __shfl_xor(psum, 16);
    psum += __shfl_xor(psum, 32);
    l_r = l_r * fac + psum;
    m_r = m_new;

    // P^T -> per-wave LDS as bf16, row = q (lr), col = key
#pragma unroll
    for (int mf = 0; mf < 2; mf++) {
#pragma unroll
      for (int jj = 0; jj < 2; jj++) {
        uint32_t pk = (uint32_t)f2bf(sm[mf * 4 + 2 * jj]) |
                      ((uint32_t)f2bf(sm[mf * 4 + 2 * jj + 1]) << 16);
        *(uint32_t*)(pl + lr * 40 + mf * 16 + lg * 4 + 2 * jj) = pk;
      }
    }
    // rescale O (O rows are q = lg*4+j)
    float fo[4];
#pragma unroll
    for (int j = 0; j < 4; j++) fo[j] = __shfl(fac, lg * 4 + j);
#pragma unroll
    for (int nf = 0; nf < 8; nf++)
#pragma unroll
      for (int j = 0; j < 4; j++) o[nf][j] *= fo[j];

    bf16x8 pa = *(const bf16x8*)(pl + lr * 40 + lg * 8);
#pragma unroll
    for (int nf = 0; nf < 8; nf++) {
      bf16x8 vb = *(const bf16x8*)(Vp + ((size_t)(nf * 16 + lr)) * 2048 + kv + lg * 8);
      o[nf] = __builtin_amdgcn_mfma_f32_16x16x32_bf16(pa, vb, o[nf], 0, 0, 0);
    }
  }

  float inv = 1.0f / l_r;
  float io[4];
#pragma unroll
  for (int j = 0; j < 4; j++) io[j] = __shfl(inv, lg * 4 + j);
#pragma unroll
  for (int nf = 0; nf < 8; nf++) {
#pragma unroll
    for (int j = 0; j < 4; j++) {
      int s = q0 + lg * 4 + j;
      ctx[((size_t)(b * 2048 + s)) * 2048 + h * 128 + nf * 16 + lr] =
          f2bf(o[nf][j] * inv * 0.0f + o[nf][j] * io[j]);  // o*io[j]
    }
  }
}

// ---------------------------------------------------------------- launch
extern "C" void kernel_launch(void* const* d_in, const int* in_sizes, int n_in,
                              void* d_out, int out_size, void* d_ws,
                              size_t ws_size, hipStream_t stream) {
  const float* x = (const float*)d_in[0];
  const float* Wq = (const float*)d_in[1];
  const float* Wk = (const float*)d_in[2];
  const float* Wv = (const float*)d_in[3];
  const float* Wo = (const float*)d_in[4];
  float* out = (float*)d_out;

  const size_t BS = 4096;  // B*S
  const size_t D = 2048;

  char* p = (char*)d_ws;
  unsigned short* xb = (unsigned short*)p;   p += BS * D * 2;       // 16.8MB
  unsigned short* wqkv = (unsigned short*)p; p += 3 * D * D * 2;    // 25.2MB
  unsigned short* wo = (unsigned short*)p;   p += D * D * 2;        // 8.4MB
  unsigned short* qb = (unsigned short*)p;   p += BS * D * 2;
  unsigned short* kb = (unsigned short*)p;   p += BS * D * 2;
  unsigned short* vb = (unsigned short*)p;   p += BS * D * 2;
  float* ctab = (float*)p;                   p += 2048 * 64 * 4;
  float* stab = (float*)p;                   p += 2048 * 64 * 4;
  unsigned short* vt = wqkv;  // reuse (dead after gemm_qkv)
  unsigned short* ctx = xb;   // reuse (dead after gemm_qkv)

  cvt_f32_bf16<<<8388608 / 1024, 256, 0, stream>>>(x, xb, 8388608);
  cvt_f32_bf16<<<4194304 / 1024, 256, 0, stream>>>(Wq, wqkv, 4194304);
  cvt_f32_bf16<<<4194304 / 1024, 256, 0, stream>>>(Wk, wqkv + 4194304, 4194304);
  cvt_f32_bf16<<<4194304 / 1024, 256, 0, stream>>>(Wv, wqkv + 8388608, 4194304);
  cvt_f32_bf16<<<4194304 / 1024, 256, 0, stream>>>(Wo, wo, 4194304);
  rope_table_k<<<131072 / 256, 256, 0, stream>>>(ctab, stab);

  gemm_bt<1><<<dim3(32, 48), 256, 0, stream>>>(xb, wqkv, nullptr, qb, kb, vb,
                                               4096, 6144, 2048);
  rope_apply_k<<<32768, 256, 0, stream>>>(qb, kb, ctab, stab);
  transpose_v_k<<<dim3(32, 32, 2), 256, 0, stream>>>(vb, vt);
  attn_k<<<dim3(32, 32), 256, 0, stream>>>(qb, kb, vt, ctx);
  gemm_bt<0><<<dim3(32, 16), 256, 0, stream>>>(ctx, wo, out, nullptr, nullptr,
                                               nullptr, 4096, 2048, 2048);
}

// Round 2
// 356.522 us; speedup vs baseline: 1.8658x; 1.8658x over previous
//
#include <hip/hip_runtime.h>
#include <cstdint>

typedef __attribute__((ext_vector_type(8))) short bf16x8;
typedef __attribute__((ext_vector_type(4))) float f32x4;

__device__ inline unsigned short f2bf(float f) {
  uint32_t u = __float_as_uint(f);
  uint32_t lsb = (u >> 16) & 1u;
  u += 0x7fffu + lsb;
  return (unsigned short)(u >> 16);
}
__device__ inline float bf2f(unsigned short b) {
  return __uint_as_float(((uint32_t)b) << 16);
}

#define GLOAD16(gp, lp)                                                        \
  __builtin_amdgcn_global_load_lds(                                            \
      (const __attribute__((address_space(1))) void*)(gp),                     \
      (__attribute__((address_space(3))) void*)(lp), 16, 0, 0)

// ---------------------------------------------------------------- converts
__global__ void cvt_f32_bf16(const float* __restrict__ in,
                             unsigned short* __restrict__ out, int n) {
  int i = (blockIdx.x * 256 + threadIdx.x) * 4;
  if (i >= n) return;
  float4 v = *(const float4*)(in + i);
  unsigned short o[4] = {f2bf(v.x), f2bf(v.y), f2bf(v.z), f2bf(v.w)};
  *(uint64_t*)(out + i) = *(const uint64_t*)o;
}

// ---------------------------------------------------------------- rope table
__global__ void rope_table_k(float* __restrict__ ctab, float* __restrict__ stab) {
  int i = blockIdx.x * 256 + threadIdx.x;  // 2048*64 entries
  int s = i >> 6, j = i & 63;
  float invf = expf(-(float)j * (9.210340371976184f / 64.0f));
  float ang = (float)s * invf;
  ctab[i] = cosf(ang);
  stab[i] = sinf(ang);
}

// ---------------------------------------------------------------- rope apply (in-place on bf16 Q,K)
// rows: [buf(2)][bh(32)][s(2048)], 4 rows per 256-thread block
__global__ void rope_apply_k(unsigned short* __restrict__ qb,
                             unsigned short* __restrict__ kb,
                             const float* __restrict__ ctab,
                             const float* __restrict__ stab) {
  int row = blockIdx.x * 4 + (threadIdx.x >> 6);
  int t = threadIdx.x & 63;
  int s = row & 2047;
  int bh = (row >> 11) & 31;
  unsigned short* base = (row >> 16) ? kb : qb;
  unsigned short* p = base + ((size_t)bh * 2048 + s) * 128;
  float c = ctab[s * 64 + t], sn = stab[s * 64 + t];
  float x1 = bf2f(p[t]), x2 = bf2f(p[t + 64]);
  p[t] = f2bf(x1 * c - x2 * sn);
  p[t + 64] = f2bf(x2 * c + x1 * sn);
}

// ---------------------------------------------------------------- V transpose: [bh][s][d] -> [bh][d][s]
__global__ void transpose_v_k(const unsigned short* __restrict__ v,
                              unsigned short* __restrict__ vt) {
  __shared__ unsigned short tile[64][72];
  int bh = blockIdx.x, st = blockIdx.y, dt = blockIdx.z;
  const unsigned short* src = v + ((size_t)bh * 2048 + st * 64) * 128 + dt * 64;
  unsigned short* dst = vt + ((size_t)bh * 128 + dt * 64) * 2048 + st * 64;
  int t = threadIdx.x;
  int r = t >> 2, c0 = (t & 3) * 16;
  *(bf16x8*)&tile[r][c0] = *(const bf16x8*)(src + (size_t)r * 128 + c0);
  *(bf16x8*)&tile[r][c0 + 8] = *(const bf16x8*)(src + (size_t)r * 128 + c0 + 8);
  __syncthreads();
  unsigned short o[16];
#pragma unroll
  for (int i = 0; i < 16; i++) o[i] = tile[c0 + i][r];
  *(bf16x8*)(dst + (size_t)r * 2048 + c0) = *(const bf16x8*)&o[0];
  *(bf16x8*)(dst + (size_t)r * 2048 + c0 + 8) = *(const bf16x8*)&o[8];
}

// ---------------------------------------------------------------- GEMM C = A(MxK) * B(NxK)^T, bf16 in, m97 structure
// EPI 0: f32 row-major C.  EPI 1: bf16 scatter into Q/K/V [B][H][S][hd].
template <int EPI>
__global__ __launch_bounds__(256, 2) void gemm_bt(
    const unsigned short* __restrict__ A, const unsigned short* __restrict__ Bm,
    float* __restrict__ Cf, unsigned short* __restrict__ q_out,
    unsigned short* __restrict__ k_out, unsigned short* __restrict__ v_out,
    int M, int N, int K) {
  __shared__ unsigned short sA[128 * 32];
  __shared__ unsigned short sB[128 * 32];
  const int t = threadIdx.x;
  const int w = t >> 6, l = t & 63;
  const int wr = w >> 1, wc = w & 1;
  const int bm = blockIdx.x * 128, bn = blockIdx.y * 128;
  const int lr = l & 15, lg = l >> 4;
  f32x4 acc[4][4] = {};

  const int srow = w * 16 + (l >> 2);
  const int sseg = (l & 3) * 8;
  const unsigned short* ga = A + (size_t)(bm + srow) * K + sseg;
  const unsigned short* gb = Bm + (size_t)(bn + srow) * K + sseg;
  unsigned short* lA = sA + w * 512 + l * 8;
  unsigned short* lB = sB + w * 512 + l * 8;

  for (int kt = 0; kt < K; kt += 32) {
    __syncthreads();
    GLOAD16(ga + kt, lA);
    GLOAD16(ga + kt + (size_t)64 * K, lA + 2048);
    GLOAD16(gb + kt, lB);
    GLOAD16(gb + kt + (size_t)64 * K, lB + 2048);
    __syncthreads();
    bf16x8 af[4], bfv[4];
#pragma unroll
    for (int m = 0; m < 4; m++)
      af[m] = *(const bf16x8*)(sA + (wr * 64 + m * 16 + lr) * 32 + lg * 8);
#pragma unroll
    for (int n = 0; n < 4; n++)
      bfv[n] = *(const bf16x8*)(sB + (wc * 64 + n * 16 + lr) * 32 + lg * 8);
#pragma unroll
    for (int m = 0; m < 4; m++)
#pragma unroll
      for (int n = 0; n < 4; n++)
        acc[m][n] = __builtin_amdgcn_mfma_f32_16x16x32_bf16(af[m], bfv[n],
                                                            acc[m][n], 0, 0, 0);
  }

#pragma unroll
  for (int m = 0; m < 4; m++) {
#pragma unroll
    for (int n = 0; n < 4; n++) {
      int gm0 = bm + wr * 64 + m * 16 + lg * 4;
      int gn = bn + wc * 64 + n * 16 + lr;
#pragma unroll
      for (int j = 0; j < 4; j++) {
        float v = acc[m][n][j];
        int gm = gm0 + j;
        if (EPI == 0) {
          Cf[(size_t)gm * N + gn] = v;
        } else {
          int which = gn >> 11, rem = gn & 2047;
          int h = rem >> 7, d = rem & 127;
          int b = gm >> 11, s = gm & 2047;
          unsigned short* dst = which == 0 ? q_out : (which == 1 ? k_out : v_out);
          dst[(((size_t)(b * 16 + h)) * 2048 + s) * 128 + d] = f2bf(v);
        }
      }
    }
  }
}

// ---------------------------------------------------------------- flash attention (round 2)
// grid (bh=32, qt=32), 256 threads = 4 waves x 16 q-rows. KVBLK=64.
// Block-cooperative double-buffered LDS staging of K [64][128] and Vt [128][64]
// via global_load_lds, XOR-swizzled (chunk ^= row&7) through pre-swizzled
// global source addresses (m173 pattern). Swapped QK^T -> lane-local softmax.
__global__ __launch_bounds__(256, 2) void attn_k(
    const unsigned short* __restrict__ Q, const unsigned short* __restrict__ K,
    const unsigned short* __restrict__ Vt, unsigned short* __restrict__ ctx) {
  __shared__ unsigned short sK[2][64 * 128];   // 2 x 16KB
  __shared__ unsigned short sV[2][128 * 64];   // 2 x 16KB
  __shared__ unsigned short sP[4][16 * 72];    // per-wave P, stride 72 shorts

  const int bh = blockIdx.x, qt = blockIdx.y;
  const int t = threadIdx.x;
  const int w = t >> 6, l = t & 63;
  const int lr = l & 15, lg = l >> 4;
  const int b = bh >> 4, h = bh & 15;
  const int q0 = qt * 64 + w * 16;
  const unsigned short* Qp = Q + ((size_t)bh * 2048 + q0) * 128;
  const unsigned short* Kbh = K + (size_t)bh * 2048 * 128;
  const unsigned short* Vbh = Vt + (size_t)bh * 128 * 2048;

  // staging source offsets (pre-swizzled: chunk ^= row&7), 4 passes each
  int gko[4], gvo[4];
#pragma unroll
  for (int i = 0; i < 4; i++) {
    int p = i * 256 + t;
    int rK = p >> 4, cK = p & 15;               // K tile: 16 chunks/row
    gko[i] = rK * 128 + ((cK ^ (rK & 7)) * 8);
    int rV = p >> 3, cV = p & 7;                // V tile: 8 chunks/row
    gvo[i] = rV * 2048 + ((cV ^ (rV & 7)) * 8);
  }

  bf16x8 qf[4];
#pragma unroll
  for (int ks = 0; ks < 4; ks++)
    qf[ks] = *(const bf16x8*)(Qp + lr * 128 + ks * 32 + lg * 8);

  f32x4 o[8];
#pragma unroll
  for (int i = 0; i < 8; i++) o[i] = (f32x4)0.0f;
  float m_r = -1e30f, l_r = 0.0f;
  const float kSc = 0.08838834764831845f * 1.4426950408889634f;  // scale*log2e
  char* pl = (char*)sP[w];

#define STAGE_KV(buf, kv)                                                      \
  do {                                                                         \
    _Pragma("unroll") for (int i = 0; i < 4; i++)                              \
        GLOAD16(Kbh + (size_t)(kv)*128 + gko[i],                               \
                sK[buf] + (i * 256 + t) * 8);                                  \
    _Pragma("unroll") for (int i = 0; i < 4; i++)                              \
        GLOAD16(Vbh + (size_t)(kv) + gvo[i], sV[buf] + (i * 256 + t) * 8);     \
  } while (0)

  STAGE_KV(0, 0);
  __syncthreads();

  for (int it = 0; it < 32; ++it) {
    const int cur = it & 1;
    if (it < 31) STAGE_KV(cur ^ 1, (it + 1) * 64);

    const char* kb = (const char*)sK[cur];
    const char* vbb = (const char*)sV[cur];

    // QK^T: S^T tile 64 keys x 16 q. lane: q=lr, keys mf*16+lg*4+j
    f32x4 st[4];
#pragma unroll
    for (int mf = 0; mf < 4; mf++) {
      st[mf] = (f32x4)0.0f;
      const int rr = mf * 16 + lr;
      const int sw = (rr & 7) << 4;
#pragma unroll
      for (int ks = 0; ks < 4; ks++) {
        bf16x8 kf = *(const bf16x8*)(kb + rr * 256 + ((ks * 64 + lg * 16) ^ sw));
        st[mf] = __builtin_amdgcn_mfma_f32_16x16x32_bf16(kf, qf[ks], st[mf], 0, 0, 0);
      }
    }

    float sm[16];
    float tmax = -1e30f;
#pragma unroll
    for (int i = 0; i < 16; i++) {
      sm[i] = st[i >> 2][i & 3] * kSc;
      tmax = fmaxf(tmax, sm[i]);
    }
    tmax = fmaxf(tmax, __shfl_xor(tmax, 16));
    tmax = fmaxf(tmax, __shfl_xor(tmax, 32));
    float m_new = fmaxf(m_r, tmax);
    float fac = exp2f(m_r - m_new);
    float psum = 0.0f;
#pragma unroll
    for (int i = 0; i < 16; i++) {
      sm[i] = exp2f(sm[i] - m_new);
      psum += sm[i];
    }
    psum += __shfl_xor(psum, 16);
    psum += __shfl_xor(psum, 32);
    l_r = l_r * fac + psum;
    m_r = m_new;

    // P -> per-wave LDS: row q=lr (stride 144B), col key
#pragma unroll
    for (int mf = 0; mf < 4; mf++) {
      unsigned short pk[4];
#pragma unroll
      for (int j = 0; j < 4; j++) pk[j] = f2bf(sm[mf * 4 + j]);
      *(uint64_t*)(pl + lr * 144 + mf * 32 + lg * 8) = *(const uint64_t*)pk;
    }

    // rescale O (O rows are q = lg*4+j)
    float fo[4];
#pragma unroll
    for (int j = 0; j < 4; j++) fo[j] = __shfl(fac, lg * 4 + j);
#pragma unroll
    for (int nf = 0; nf < 8; nf++)
#pragma unroll
      for (int j = 0; j < 4; j++) o[nf][j] *= fo[j];

    bf16x8 pa[2];
#pragma unroll
    for (int ks2 = 0; ks2 < 2; ks2++)
      pa[ks2] = *(const bf16x8*)(pl + lr * 144 + ks2 * 64 + lg * 16);
#pragma unroll
    for (int nf = 0; nf < 8; nf++) {
      const int rv = nf * 16 + lr;
      const int sw = (rv & 7) << 4;
#pragma unroll
      for (int ks2 = 0; ks2 < 2; ks2++) {
        bf16x8 vb = *(const bf16x8*)(vbb + rv * 128 + ((ks2 * 64 + lg * 16) ^ sw));
        o[nf] = __builtin_amdgcn_mfma_f32_16x16x32_bf16(pa[ks2], vb, o[nf], 0, 0, 0);
      }
    }
    __syncthreads();  // drains vmcnt (stage) + lets buffers rotate
  }

  float inv = 1.0f / l_r;
  float io[4];
#pragma unroll
  for (int j = 0; j < 4; j++) io[j] = __shfl(inv, lg * 4 + j);
#pragma unroll
  for (int nf = 0; nf < 8; nf++) {
#pragma unroll
    for (int j = 0; j < 4; j++) {
      int s = q0 + lg * 4 + j;
      ctx[((size_t)(b * 2048 + s)) * 2048 + h * 128 + nf * 16 + lr] =
          f2bf(o[nf][j] * io[j]);
    }
  }
}

// ---------------------------------------------------------------- launch
extern "C" void kernel_launch(void* const* d_in, const int* in_sizes, int n_in,
                              void* d_out, int out_size, void* d_ws,
                              size_t ws_size, hipStream_t stream) {
  const float* x = (const float*)d_in[0];
  const float* Wq = (const float*)d_in[1];
  const float* Wk = (const float*)d_in[2];
  const float* Wv = (const float*)d_in[3];
  const float* Wo = (const float*)d_in[4];
  float* out = (float*)d_out;

  const size_t BS = 4096;  // B*S
  const size_t D = 2048;

  char* p = (char*)d_ws;
  unsigned short* xb = (unsigned short*)p;   p += BS * D * 2;
  unsigned short* wqkv = (unsigned short*)p; p += 3 * D * D * 2;
  unsigned short* wo = (unsigned short*)p;   p += D * D * 2;
  unsigned short* qb = (unsigned short*)p;   p += BS * D * 2;
  unsigned short* kb = (unsigned short*)p;   p += BS * D * 2;
  unsigned short* vb = (unsigned short*)p;   p += BS * D * 2;
  float* ctab = (float*)p;                   p += 2048 * 64 * 4;
  float* stab = (float*)p;                   p += 2048 * 64 * 4;
  unsigned short* vt = wqkv;  // reuse (dead after gemm_qkv)
  unsigned short* ctx = xb;   // reuse (dead after gemm_qkv)

  cvt_f32_bf16<<<8388608 / 1024, 256, 0, stream>>>(x, xb, 8388608);
  cvt_f32_bf16<<<4194304 / 1024, 256, 0, stream>>>(Wq, wqkv, 4194304);
  cvt_f32_bf16<<<4194304 / 1024, 256, 0, stream>>>(Wk, wqkv + 4194304, 4194304);
  cvt_f32_bf16<<<4194304 / 1024, 256, 0, stream>>>(Wv, wqkv + 8388608, 4194304);
  cvt_f32_bf16<<<4194304 / 1024, 256, 0, stream>>>(Wo, wo, 4194304);
  rope_table_k<<<131072 / 256, 256, 0, stream>>>(ctab, stab);

  gemm_bt<1><<<dim3(32, 48), 256, 0, stream>>>(xb, wqkv, nullptr, qb, kb, vb,
                                               4096, 6144, 2048);
  rope_apply_k<<<32768, 256, 0, stream>>>(qb, kb, ctab, stab);
  transpose_v_k<<<dim3(32, 32, 2), 256, 0, stream>>>(vb, vt);
  attn_k<<<dim3(32, 32), 256, 0, stream>>>(qb, kb, vt, ctx);
  gemm_bt<0><<<dim3(32, 16), 256, 0, stream>>>(ctx, wo, out, nullptr, nullptr,
                                               nullptr, 4096, 2048, 2048);
}

// Round 3
// 316.272 us; speedup vs baseline: 2.1032x; 1.1273x over previous
//
#include <hip/hip_runtime.h>
#include <cstdint>

typedef __attribute__((ext_vector_type(8))) short bf16x8;
typedef __attribute__((ext_vector_type(4))) float f32x4;
typedef __attribute__((ext_vector_type(16))) float f32x16;

__device__ inline unsigned short f2bf(float f) {
  uint32_t u = __float_as_uint(f);
  uint32_t lsb = (u >> 16) & 1u;
  u += 0x7fffu + lsb;
  return (unsigned short)(u >> 16);
}
__device__ inline float bf2f(unsigned short b) {
  return __uint_as_float(((uint32_t)b) << 16);
}
__device__ inline uint32_t cvt_pk_bf16(float lo, float hi) {
  uint32_t r;
  asm volatile("v_cvt_pk_bf16_f32 %0, %1, %2" : "=v"(r) : "v"(lo), "v"(hi));
  return r;
}

#define GLOAD16(gp, lp)                                                        \
  __builtin_amdgcn_global_load_lds(                                            \
      (const __attribute__((address_space(1))) void*)(gp),                     \
      (__attribute__((address_space(3))) void*)(lp), 16, 0, 0)

// ---------------------------------------------------------------- converts
__global__ void cvt_f32_bf16(const float* __restrict__ in,
                             unsigned short* __restrict__ out, int n) {
  int i = (blockIdx.x * 256 + threadIdx.x) * 4;
  if (i >= n) return;
  float4 v = *(const float4*)(in + i);
  unsigned short o[4] = {f2bf(v.x), f2bf(v.y), f2bf(v.z), f2bf(v.w)};
  *(uint64_t*)(out + i) = *(const uint64_t*)o;
}

// ---------------------------------------------------------------- rope table
__global__ void rope_table_k(float* __restrict__ ctab, float* __restrict__ stab) {
  int i = blockIdx.x * 256 + threadIdx.x;  // 2048*64 entries
  int s = i >> 6, j = i & 63;
  float invf = expf(-(float)j * (9.210340371976184f / 64.0f));
  float ang = (float)s * invf;
  ctab[i] = cosf(ang);
  stab[i] = sinf(ang);
}

// ---------------------------------------------------------------- rope apply (in-place on bf16 Q,K)
// rows: [buf(2)][bh(32)][s(2048)], 4 rows per 256-thread block.
// Q additionally scaled by 1/sqrt(hd) * log2(e) so attention scores are in
// exp2 domain with the softmax scale pre-folded.
__global__ void rope_apply_k(unsigned short* __restrict__ qb,
                             unsigned short* __restrict__ kb,
                             const float* __restrict__ ctab,
                             const float* __restrict__ stab) {
  int row = blockIdx.x * 4 + (threadIdx.x >> 6);
  int t = threadIdx.x & 63;
  int s = row & 2047;
  int bh = (row >> 11) & 31;
  int isK = row >> 16;
  unsigned short* base = isK ? kb : qb;
  float qs = isK ? 1.0f : (0.08838834764831845f * 1.4426950408889634f);
  unsigned short* p = base + ((size_t)bh * 2048 + s) * 128;
  float c = ctab[s * 64 + t], sn = stab[s * 64 + t];
  float x1 = bf2f(p[t]), x2 = bf2f(p[t + 64]);
  p[t] = f2bf((x1 * c - x2 * sn) * qs);
  p[t + 64] = f2bf((x2 * c + x1 * sn) * qs);
}

// ---------------------------------------------------------------- V transpose: [bh][s][d] -> [bh][d][s]
__global__ void transpose_v_k(const unsigned short* __restrict__ v,
                              unsigned short* __restrict__ vt) {
  __shared__ unsigned short tile[64][72];
  int bh = blockIdx.x, st = blockIdx.y, dt = blockIdx.z;
  const unsigned short* src = v + ((size_t)bh * 2048 + st * 64) * 128 + dt * 64;
  unsigned short* dst = vt + ((size_t)bh * 128 + dt * 64) * 2048 + st * 64;
  int t = threadIdx.x;
  int r = t >> 2, c0 = (t & 3) * 16;
  *(bf16x8*)&tile[r][c0] = *(const bf16x8*)(src + (size_t)r * 128 + c0);
  *(bf16x8*)&tile[r][c0 + 8] = *(const bf16x8*)(src + (size_t)r * 128 + c0 + 8);
  __syncthreads();
  unsigned short o[16];
#pragma unroll
  for (int i = 0; i < 16; i++) o[i] = tile[c0 + i][r];
  *(bf16x8*)(dst + (size_t)r * 2048 + c0) = *(const bf16x8*)&o[0];
  *(bf16x8*)(dst + (size_t)r * 2048 + c0 + 8) = *(const bf16x8*)&o[8];
}

// ---------------------------------------------------------------- GEMM C = A(MxK) * B(NxK)^T, bf16 in, m97 structure
template <int EPI>
__global__ __launch_bounds__(256, 2) void gemm_bt(
    const unsigned short* __restrict__ A, const unsigned short* __restrict__ Bm,
    float* __restrict__ Cf, unsigned short* __restrict__ q_out,
    unsigned short* __restrict__ k_out, unsigned short* __restrict__ v_out,
    int M, int N, int K) {
  __shared__ unsigned short sA[128 * 32];
  __shared__ unsigned short sB[128 * 32];
  const int t = threadIdx.x;
  const int w = t >> 6, l = t & 63;
  const int wr = w >> 1, wc = w & 1;
  const int bm = blockIdx.x * 128, bn = blockIdx.y * 128;
  const int lr = l & 15, lg = l >> 4;
  f32x4 acc[4][4] = {};

  const int srow = w * 16 + (l >> 2);
  const int sseg = (l & 3) * 8;
  const unsigned short* ga = A + (size_t)(bm + srow) * K + sseg;
  const unsigned short* gb = Bm + (size_t)(bn + srow) * K + sseg;
  unsigned short* lA = sA + w * 512 + l * 8;
  unsigned short* lB = sB + w * 512 + l * 8;

  for (int kt = 0; kt < K; kt += 32) {
    __syncthreads();
    GLOAD16(ga + kt, lA);
    GLOAD16(ga + kt + (size_t)64 * K, lA + 2048);
    GLOAD16(gb + kt, lB);
    GLOAD16(gb + kt + (size_t)64 * K, lB + 2048);
    __syncthreads();
    bf16x8 af[4], bfv[4];
#pragma unroll
    for (int m = 0; m < 4; m++)
      af[m] = *(const bf16x8*)(sA + (wr * 64 + m * 16 + lr) * 32 + lg * 8);
#pragma unroll
    for (int n = 0; n < 4; n++)
      bfv[n] = *(const bf16x8*)(sB + (wc * 64 + n * 16 + lr) * 32 + lg * 8);
#pragma unroll
    for (int m = 0; m < 4; m++)
#pragma unroll
      for (int n = 0; n < 4; n++)
        acc[m][n] = __builtin_amdgcn_mfma_f32_16x16x32_bf16(af[m], bfv[n],
                                                            acc[m][n], 0, 0, 0);
  }

#pragma unroll
  for (int m = 0; m < 4; m++) {
#pragma unroll
    for (int n = 0; n < 4; n++) {
      int gm0 = bm + wr * 64 + m * 16 + lg * 4;
      int gn = bn + wc * 64 + n * 16 + lr;
#pragma unroll
      for (int j = 0; j < 4; j++) {
        float v = acc[m][n][j];
        int gm = gm0 + j;
        if (EPI == 0) {
          Cf[(size_t)gm * N + gn] = v;
        } else {
          int which = gn >> 11, rem = gn & 2047;
          int h = rem >> 7, d = rem & 127;
          int b = gm >> 11, s = gm & 2047;
          unsigned short* dst = which == 0 ? q_out : (which == 1 ? k_out : v_out);
          dst[(((size_t)(b * 16 + h)) * 2048 + s) * 128 + d] = f2bf(v);
        }
      }
    }
  }
}

// ---------------------------------------------------------------- flash attention (round 3: 32x32 MFMA)
// grid (qt=16, bh=32), 256 threads = 4 waves x 32 q-rows (q-tile 128).
// K [64][128] and Vt [128][64] double-buffered in LDS (XOR-swizzled via
// pre-swizzled global source). Swapped QK^T with 32x32x16: lane holds all
// 64 scores of q=lane&31 split with lane^32; softmax fully in-register;
// P->PV A-fragments built via cvt_pk + shfl_xor(32) (no P LDS).
__global__ __launch_bounds__(256, 2) void attn_k(
    const unsigned short* __restrict__ Q, const unsigned short* __restrict__ K,
    const unsigned short* __restrict__ Vt, unsigned short* __restrict__ ctx) {
  __shared__ unsigned short sK[2][64 * 128];  // 2 x 16KB
  __shared__ unsigned short sV[2][128 * 64];  // 2 x 16KB

  const int qt = blockIdx.x, bh = blockIdx.y;
  const int t = threadIdx.x;
  const int w = t >> 6, l = t & 63;
  const int lq = l & 31;   // q-row (QK) / d-col (PV)
  const int h5 = l >> 5;   // half-wave select
  const int b = bh >> 4, hh = bh & 15;
  const int q0 = qt * 128 + w * 32;
  const unsigned short* Qp = Q + ((size_t)bh * 2048 + q0) * 128;
  const unsigned short* Kbh = K + (size_t)bh * 2048 * 128;
  const unsigned short* Vbh = Vt + (size_t)bh * 128 * 2048;

  // staging source offsets (pre-swizzled: chunk ^= row&7), 4 passes each
  int gko[4], gvo[4];
#pragma unroll
  for (int i = 0; i < 4; i++) {
    int p = i * 256 + t;
    int rK = p >> 4, cK = p & 15;  // K tile: 16 chunks/row
    gko[i] = rK * 128 + ((cK ^ (rK & 7)) * 8);
    int rV = p >> 3, cV = p & 7;   // V tile: 8 chunks/row
    gvo[i] = rV * 2048 + ((cV ^ (rV & 7)) * 8);
  }

  // Q fragments: qf[st] = Q[q=lq][st*16 + h5*8 + 0..7]  (B-operand)
  bf16x8 qf[8];
#pragma unroll
  for (int st = 0; st < 8; st++)
    qf[st] = *(const bf16x8*)(Qp + lq * 128 + st * 16 + h5 * 8);

  f32x16 o[4];
#pragma unroll
  for (int db = 0; db < 4; db++) o[db] = (f32x16)0.0f;
  float m_r = -1e30f, l_r = 0.0f;

#define STAGE_KV(buf, kv)                                                      \
  do {                                                                         \
    _Pragma("unroll") for (int i = 0; i < 4; i++)                              \
        GLOAD16(Kbh + (size_t)(kv)*128 + gko[i],                               \
                sK[buf] + (i * 256 + t) * 8);                                  \
    _Pragma("unroll") for (int i = 0; i < 4; i++)                              \
        GLOAD16(Vbh + (size_t)(kv) + gvo[i], sV[buf] + (i * 256 + t) * 8);     \
  } while (0)

  STAGE_KV(0, 0);
  __syncthreads();

  for (int it = 0; it < 32; ++it) {
    const int cur = it & 1;
    if (it < 31) STAGE_KV(cur ^ 1, (it + 1) * 64);

    const char* kbuf = (const char*)sK[cur];
    const char* vbuf = (const char*)sV[cur];

    // QK^T: D[key][q], A = K rows (keys), B = Q. 2 key-blocks x 8 d-steps.
    f32x16 s2[2];
#pragma unroll
    for (int kb2 = 0; kb2 < 2; kb2++) {
      s2[kb2] = (f32x16)0.0f;
      const int rr = kb2 * 32 + lq;
      const int swz = (rr & 7) << 4;
#pragma unroll
      for (int st = 0; st < 8; st++) {
        bf16x8 kf = *(const bf16x8*)(kbuf + rr * 256 + ((st * 32 + h5 * 16) ^ swz));
        s2[kb2] = __builtin_amdgcn_mfma_f32_32x32x16_bf16(kf, qf[st], s2[kb2], 0, 0, 0);
      }
    }

    // lane's 32 scores: q = lq, key = kb*32 + (r&3) + 8*(r>>2) + 4*h5
    float sm[32];
#pragma unroll
    for (int kb2 = 0; kb2 < 2; kb2++)
#pragma unroll
      for (int r = 0; r < 16; r++) sm[kb2 * 16 + r] = s2[kb2][r];

    float tmax = sm[0];
#pragma unroll
    for (int i = 1; i < 32; i++) tmax = fmaxf(tmax, sm[i]);
    tmax = fmaxf(tmax, __shfl_xor(tmax, 32));

    // defer-max (T13): only rescale when tile max exceeds running max + 8
    if (!__all(tmax <= m_r + 8.0f)) {
      float m_new = fmaxf(m_r, tmax);
      float fac = exp2f(m_r - m_new);
      l_r *= fac;
      float fo[16];
#pragma unroll
      for (int r = 0; r < 16; r++)
        fo[r] = __shfl(fac, (r & 3) + 8 * (r >> 2) + 4 * h5);
#pragma unroll
      for (int db = 0; db < 4; db++)
#pragma unroll
        for (int r = 0; r < 16; r++) o[db][r] *= fo[r];
      m_r = m_new;
    }

    float psum = 0.0f;
#pragma unroll
    for (int i = 0; i < 32; i++) {
      sm[i] = exp2f(sm[i] - m_r);
      psum += sm[i];
    }
    psum += __shfl_xor(psum, 32);
    l_r += psum;

    // pack P to bf16 words: wAp[kb][rq] = keys kb*32+8rq+4h5+{0,1}, wBp +{2,3}
    uint32_t wAp[2][4], wBp[2][4];
#pragma unroll
    for (int kb2 = 0; kb2 < 2; kb2++)
#pragma unroll
      for (int rq = 0; rq < 4; rq++) {
        wAp[kb2][rq] = cvt_pk_bf16(sm[kb2 * 16 + rq * 4 + 0], sm[kb2 * 16 + rq * 4 + 1]);
        wBp[kb2][rq] = cvt_pk_bf16(sm[kb2 * 16 + rq * 4 + 2], sm[kb2 * 16 + rq * 4 + 3]);
      }

    // PV: 4 k-steps of 16 keys; A-frag needs keys st*16 + h5*8 + 0..7
#pragma unroll
    for (int st = 0; st < 4; st++) {
      const int kb2 = st >> 1, p2 = (st & 1) * 2;
      uint32_t keepA = h5 ? wAp[kb2][p2 + 1] : wAp[kb2][p2];
      uint32_t keepB = h5 ? wBp[kb2][p2 + 1] : wBp[kb2][p2];
      uint32_t sendA = h5 ? wAp[kb2][p2] : wAp[kb2][p2 + 1];
      uint32_t sendB = h5 ? wBp[kb2][p2] : wBp[kb2][p2 + 1];
      uint32_t partA = __shfl_xor(sendA, 32);
      uint32_t partB = __shfl_xor(sendB, 32);
      union {
        uint32_t u[4];
        bf16x8 v;
      } pu;
      pu.u[0] = h5 ? partA : keepA;
      pu.u[1] = h5 ? partB : keepB;
      pu.u[2] = h5 ? keepA : partA;
      pu.u[3] = h5 ? keepB : partB;
#pragma unroll
      for (int db = 0; db < 4; db++) {
        const int rv = db * 32 + lq;
        const int swz = (rv & 7) << 4;
        bf16x8 vb = *(const bf16x8*)(vbuf + rv * 128 + ((st * 32 + h5 * 16) ^ swz));
        o[db] = __builtin_amdgcn_mfma_f32_32x32x16_bf16(pu.v, vb, o[db], 0, 0, 0);
      }
    }
    __syncthreads();  // drains vmcnt (stage) + rotates buffers
  }

  float inv = 1.0f / l_r;
  float io[16];
#pragma unroll
  for (int r = 0; r < 16; r++)
    io[r] = __shfl(inv, (r & 3) + 8 * (r >> 2) + 4 * h5);
#pragma unroll
  for (int db = 0; db < 4; db++) {
#pragma unroll
    for (int r = 0; r < 16; r++) {
      int s = q0 + (r & 3) + 8 * (r >> 2) + 4 * h5;
      ctx[((size_t)(b * 2048 + s)) * 2048 + hh * 128 + db * 32 + lq] =
          f2bf(o[db][r] * io[r]);
    }
  }
}

// ---------------------------------------------------------------- launch
extern "C" void kernel_launch(void* const* d_in, const int* in_sizes, int n_in,
                              void* d_out, int out_size, void* d_ws,
                              size_t ws_size, hipStream_t stream) {
  const float* x = (const float*)d_in[0];
  const float* Wq = (const float*)d_in[1];
  const float* Wk = (const float*)d_in[2];
  const float* Wv = (const float*)d_in[3];
  const float* Wo = (const float*)d_in[4];
  float* out = (float*)d_out;

  const size_t BS = 4096;  // B*S
  const size_t D = 2048;

  char* p = (char*)d_ws;
  unsigned short* xb = (unsigned short*)p;   p += BS * D * 2;
  unsigned short* wqkv = (unsigned short*)p; p += 3 * D * D * 2;
  unsigned short* wo = (unsigned short*)p;   p += D * D * 2;
  unsigned short* qb = (unsigned short*)p;   p += BS * D * 2;
  unsigned short* kb = (unsigned short*)p;   p += BS * D * 2;
  unsigned short* vb = (unsigned short*)p;   p += BS * D * 2;
  float* ctab = (float*)p;                   p += 2048 * 64 * 4;
  float* stab = (float*)p;                   p += 2048 * 64 * 4;
  unsigned short* vt = wqkv;  // reuse (dead after gemm_qkv)
  unsigned short* ctx = xb;   // reuse (dead after gemm_qkv)

  cvt_f32_bf16<<<8388608 / 1024, 256, 0, stream>>>(x, xb, 8388608);
  cvt_f32_bf16<<<4194304 / 1024, 256, 0, stream>>>(Wq, wqkv, 4194304);
  cvt_f32_bf16<<<4194304 / 1024, 256, 0, stream>>>(Wk, wqkv + 4194304, 4194304);
  cvt_f32_bf16<<<4194304 / 1024, 256, 0, stream>>>(Wv, wqkv + 8388608, 4194304);
  cvt_f32_bf16<<<4194304 / 1024, 256, 0, stream>>>(Wo, wo, 4194304);
  rope_table_k<<<131072 / 256, 256, 0, stream>>>(ctab, stab);

  gemm_bt<1><<<dim3(32, 48), 256, 0, stream>>>(xb, wqkv, nullptr, qb, kb, vb,
                                               4096, 6144, 2048);
  rope_apply_k<<<32768, 256, 0, stream>>>(qb, kb, ctab, stab);
  transpose_v_k<<<dim3(32, 32, 2), 256, 0, stream>>>(vb, vt);
  attn_k<<<dim3(16, 32), 256, 0, stream>>>(qb, kb, vt, ctx);
  gemm_bt<0><<<dim3(32, 16), 256, 0, stream>>>(ctx, wo, out, nullptr, nullptr,
                                               nullptr, 4096, 2048, 2048);
}